// Round 14
// baseline (1261.837 us; speedup 1.0000x reference)
//
#include <hip/hip_runtime.h>

typedef unsigned short u16;
typedef unsigned int u32;
typedef __bf16 bf16x8 __attribute__((ext_vector_type(8)));
typedef __bf16 bf16x2v __attribute__((ext_vector_type(2)));
typedef float f32x4 __attribute__((ext_vector_type(4)));
typedef u16 u16x8 __attribute__((ext_vector_type(8)));
typedef u16 u16x4 __attribute__((ext_vector_type(4)));
typedef u32 u32x2 __attribute__((ext_vector_type(2)));

// ---------------- helpers ----------------
__device__ __forceinline__ u16 f2bf(float f) {
    union { float f; u32 u; } v; v.f = f;
    u32 r = v.u + 0x7fffu + ((v.u >> 16) & 1u);
    return (u16)(r >> 16);
}
__device__ __forceinline__ float bf2f(u16 h) {
    union { u32 u; float f; } v; v.u = ((u32)h) << 16;
    return v.f;
}
__device__ __forceinline__ u32 pk2(float a, float b) {
    bf16x2v t; t[0] = (__bf16)a; t[1] = (__bf16)b;
    union { bf16x2v v; u32 u; } c; c.v = t; return c.u;
}
__device__ __forceinline__ float gelu_f(float x) {
    float x2 = x * x;
    float z = x * fmaf(x2, 0.071354816f, 1.595769122f);
    return x * (1.0f / (1.0f + __expf(-z)));
}
__device__ __forceinline__ void async16(u16* lds, const u16* g) {
    __builtin_amdgcn_global_load_lds(
        (const __attribute__((address_space(1))) void*)g,
        (__attribute__((address_space(3))) void*)lds, 16, 0, 0);
}

// token index (window space) -> source/dest row in (B, 56, 56) raster order
__device__ __forceinline__ size_t win_to_img_row(int td) {
    int wb = td / 49, t = td - wb * 49;
    int bb = wb >> 6, w = wb & 63;
    int wh = w >> 3, ww = w & 7;
    int th = t / 7, tw = t - th * 7;
    int oh = wh * 7 + th + 3; if (oh >= 56) oh -= 56;
    int ow = ww * 7 + tw + 3; if (ow >= 56) ow -= 56;
    return ((size_t)bb * 3136 + oh * 56 + ow);
}

// ---------------- fp32 -> bf16 weight converts ----------------
__global__ void cvt_kernel(const float* __restrict__ s, u16* __restrict__ d, int n) {
    int i = blockIdx.x * 256 + threadIdx.x;
    if (i < n) d[i] = f2bf(s[i]);
}
// within-64 K-column permutation pk(k) = (k&~63) | ((k&15)*4 + ((k>>4)&3))
__global__ void cvt_p64_kernel(const float* __restrict__ s, u16* __restrict__ d, int n) {
    int i = blockIdx.x * 256 + threadIdx.x;
    if (i < n) {
        int k = i & 2047, r = i >> 11;
        int pk_ = (k & ~63) | (((k & 15) << 2) | ((k >> 4) & 3));
        d[(r << 11) + pk_] = f2bf(s[i]);
    }
}
__global__ void cvt_p64k512_kernel(const float* __restrict__ s, u16* __restrict__ d, int n) {
    int i = blockIdx.x * 256 + threadIdx.x;
    if (i < n) {
        int k = i & 511, r = i >> 9;
        int pk_ = (k & ~63) | (((k & 15) << 2) | ((k >> 4) & 3));
        d[(r << 9) + pk_] = f2bf(s[i]);
    }
}

// ---------------- bias+mask table: T[cat][head][64][64] fp32 ----------------
__global__ void tbl_kernel(const float* __restrict__ relb, float* __restrict__ T) {
    int i = blockIdx.x * 256 + threadIdx.x;      // 4*16*64*64 = 262144
    int c = i & 63, r = (i >> 6) & 63, head = (i >> 12) & 15, cat = i >> 16;
    float v;
    if (c >= 49 || r >= 49) v = -1e30f;
    else {
        int rh = r / 7, rw = r - rh * 7, ch = c / 7, cw = c - ch * 7;
        v = relb[((rh - ch + 6) * 13 + (rw - cw + 6)) * 16 + head];
        int lr = ((cat & 2) ? (rh < 4 ? 1 : 2) : 0) * 3 + ((cat & 1) ? (rw < 4 ? 1 : 2) : 0);
        int lc = ((cat & 2) ? (ch < 4 ? 1 : 2) : 0) * 3 + ((cat & 1) ? (cw < 4 ? 1 : 2) : 0);
        if (lr != lc) v -= 100.f;
    }
    T[i] = v;
}

// ---------------- LayerNorm (wave per token) + shift+window gather ----------------
// Optionally co-emits xwb: raw x as bf16, window order, p64-permuted layout.
__global__ __launch_bounds__(256) void ln_kernel(
    const float* __restrict__ src, const float* __restrict__ g,
    const float* __restrict__ b, u16* __restrict__ dst, u16* __restrict__ xdst)
{
    const int lane = threadIdx.x & 63;
    const int td = blockIdx.x * 4 + (threadIdx.x >> 6);
    const size_t so = win_to_img_row(td) * 512;

    const float4* px = (const float4*)(src + so);
    float4 v0 = px[lane * 2], v1 = px[lane * 2 + 1];
    float a[8] = {v0.x, v0.y, v0.z, v0.w, v1.x, v1.y, v1.z, v1.w};
    float s = 0.f, q = 0.f;
#pragma unroll
    for (int e = 0; e < 8; ++e) { s += a[e]; q += a[e] * a[e]; }
#pragma unroll
    for (int m = 32; m; m >>= 1) { s += __shfl_xor(s, m); q += __shfl_xor(q, m); }
    float mean = s * (1.f / 512.f);
    float var  = q * (1.f / 512.f) - mean * mean;
    float rstd = rsqrtf(var + 1e-5f);
    const int c0 = lane * 8;
    if (xdst) {
        // permuted slot: s(c) = 64*(c>>6) + 4*(c&15) + ((c>>4)&3); c = lane*8+e
        u16* xr = xdst + (size_t)td * 512
                + 64 * (lane >> 3) + 32 * (lane & 1) + ((lane >> 1) & 3);
#pragma unroll
        for (int e = 0; e < 8; ++e) xr[4 * e] = f2bf(a[e]);
    }
    u16x8 o;
#pragma unroll
    for (int e = 0; e < 8; ++e)
        o[e] = f2bf((a[e] - mean) * rstd * g[c0 + e] + b[c0 + e]);
    *(u16x8*)(dst + (size_t)td * 512 + c0) = o;
}

// ---------------- 256x256 8-wave 8-phase bf16 GEMM (R9 structure) ----------------
// EPI: 0 = bf16 packed-permuted (qkv), 1 = gelu+bf16 packed-permuted (fc1),
//      5 = final: out[img(row+rowOff)] = bf16(x2b)[row] + acc + bias (write-only scatter)
template <int EPI>
__global__ __launch_bounds__(512, 2) void gemm6(
    const u16* __restrict__ A, const u16* __restrict__ W,
    const float* __restrict__ bias, int M, int N, int K,
    void* __restrict__ Cout, int rowOff, const u16* __restrict__ X2b)
{
    __shared__ __align__(16) u16 lds[65536];   // A: [2][256][64] @0, B: [2][256][64] @32768
    const int tid = threadIdx.x;
    const int lane = tid & 63, wv = tid >> 6;
    const int wr = wv >> 2, wc = wv & 3;
    const int ln = lane & 15, kq = lane >> 4;
    const int nbn = N >> 8;
    const int nwg = gridDim.x;
    const int wgid = ((nwg & 7) == 0) ? ((blockIdx.x & 7) * (nwg >> 3) + (blockIdx.x >> 3))
                                      : blockIdx.x;
    const int bm = wgid / nbn, bn = wgid - bm * nbn;
    const int m0 = bm << 8, n0 = bn << 8;

    const int sq = (((tid & 7) ^ ((tid >> 3) & 7)) << 3);
    const u16* gA = A + (size_t)(m0 + (tid >> 3)) * K + sq;
    const u16* gB = W + (size_t)(n0 + (tid >> 3)) * K + sq;

    const int baseA0 = (wr * 128 + ln) * 64 + (((kq) ^ (ln & 7)) << 3);
    const int baseA1 = (wr * 128 + ln) * 64 + (((4 + kq) ^ (ln & 7)) << 3);
    const int baseB0 = 32768 + (wc * 64 + ln) * 64 + (((kq) ^ (ln & 7)) << 3);
    const int baseB1 = 32768 + (wc * 64 + ln) * 64 + (((4 + kq) ^ (ln & 7)) << 3);

#define STA(dd, u, t) async16(lds + (dd) * 16384 + (u) * 4096 + tid * 8, \
                              gA + (size_t)(u) * 64 * K + (size_t)(t) * 64)
#define STB(dd, u, t) async16(lds + 32768 + (dd) * 16384 + (u) * 4096 + tid * 8, \
                              gB + (size_t)(u) * 64 * K + (size_t)(t) * 64)
#define LDA(dd, ms, kh) (*(const bf16x8*)(lds + (dd) * 16384 + ((kh) ? baseA1 : baseA0) + (ms) * 1024))
#define LDB(dd, ns, kh) (*(const bf16x8*)(lds + (dd) * 16384 + ((kh) ? baseB1 : baseB0) + (ns) * 1024))
#define BAR  __builtin_amdgcn_s_barrier()
#define MMQ(mb, nb, BB) do { \
        __builtin_amdgcn_s_setprio(1); \
        _Pragma("unroll") \
        for (int kh = 0; kh < 2; ++kh) \
        _Pragma("unroll") \
        for (int ms = 0; ms < 4; ++ms) \
        _Pragma("unroll") \
        for (int nn = 0; nn < 2; ++nn) \
            acc[(mb) + ms][(nb) + nn] = __builtin_amdgcn_mfma_f32_16x16x32_bf16( \
                af[ms][kh], BB[nn][kh], acc[(mb) + ms][(nb) + nn], 0, 0, 0); \
        __builtin_amdgcn_s_setprio(0); \
    } while (0)

    const int nIter = K >> 7;
    f32x4 acc[8][4] = {};
    bf16x8 af[4][2], b01[2][2], b23[2][2];

    STA(0, 0, 0); STA(0, 2, 0); STA(0, 1, 0); STA(0, 3, 0);
    STB(0, 0, 0); STB(0, 1, 0); STB(0, 2, 0); STB(0, 3, 0);
    STA(1, 0, 1); STA(1, 2, 1); STA(1, 1, 1); STA(1, 3, 1);
    asm volatile("s_waitcnt vmcnt(4)" ::: "memory");
    BAR;

    for (int it = 0; it < nIter; ++it) {
        const int T = 2 * it;
        const bool more = (it + 1 < nIter);
        // ---- P1 ----
#pragma unroll
        for (int ms = 0; ms < 4; ++ms) { af[ms][0] = LDA(0, ms, 0); af[ms][1] = LDA(0, ms, 1); }
#pragma unroll
        for (int nn = 0; nn < 2; ++nn) { b01[nn][0] = LDB(0, nn, 0); b01[nn][1] = LDB(0, nn, 1); }
        STB(1, 0, T + 1); STB(1, 1, T + 1);
        MMQ(0, 0, b01);
        BAR;
        // ---- P2 ----
#pragma unroll
        for (int nn = 0; nn < 2; ++nn) { b23[nn][0] = LDB(0, nn + 2, 0); b23[nn][1] = LDB(0, nn + 2, 1); }
        STB(1, 2, T + 1); STB(1, 3, T + 1);
        MMQ(0, 2, b23);
        BAR;
        // ---- P3 ----
#pragma unroll
        for (int ms = 0; ms < 4; ++ms) { af[ms][0] = LDA(0, ms + 4, 0); af[ms][1] = LDA(0, ms + 4, 1); }
        if (more) { STA(0, 0, T + 2); STA(0, 2, T + 2); }
        MMQ(4, 2, b23);
        BAR;
        // ---- P4 ----
        if (more) { STA(0, 1, T + 2); STA(0, 3, T + 2); }
        MMQ(4, 0, b01);
        if (more) asm volatile("s_waitcnt vmcnt(4)" ::: "memory");
        else      asm volatile("s_waitcnt vmcnt(0)" ::: "memory");
        BAR;
        // ---- P5 ----
#pragma unroll
        for (int ms = 0; ms < 4; ++ms) { af[ms][0] = LDA(1, ms, 0); af[ms][1] = LDA(1, ms, 1); }
#pragma unroll
        for (int nn = 0; nn < 2; ++nn) { b01[nn][0] = LDB(1, nn, 0); b01[nn][1] = LDB(1, nn, 1); }
        if (more) { STB(0, 0, T + 2); STB(0, 1, T + 2); }
        MMQ(0, 0, b01);
        BAR;
        // ---- P6 ----
#pragma unroll
        for (int nn = 0; nn < 2; ++nn) { b23[nn][0] = LDB(1, nn + 2, 0); b23[nn][1] = LDB(1, nn + 2, 1); }
        if (more) { STB(0, 2, T + 2); STB(0, 3, T + 2); }
        MMQ(0, 2, b23);
        BAR;
        // ---- P7 ----
#pragma unroll
        for (int ms = 0; ms < 4; ++ms) { af[ms][0] = LDA(1, ms + 4, 0); af[ms][1] = LDA(1, ms + 4, 1); }
        if (more) { STA(1, 0, T + 3); STA(1, 2, T + 3); }
        MMQ(4, 2, b23);
        BAR;
        // ---- P8 ----
        if (more) { STA(1, 1, T + 3); STA(1, 3, T + 3); }
        MMQ(4, 0, b01);
        if (more) asm volatile("s_waitcnt vmcnt(4)" ::: "memory");
        BAR;
    }
#undef STA
#undef STB
#undef LDA
#undef LDB
#undef BAR
#undef MMQ

    // ---------- epilogue ----------
    float bs[4];
#pragma unroll
    for (int n = 0; n < 4; ++n) bs[n] = bias[n0 + wc * 64 + n * 16 + ln];
#pragma unroll
    for (int i = 0; i < 8; ++i) {
#pragma unroll
        for (int r = 0; r < 4; ++r) {
            const int row = m0 + wr * 128 + i * 16 + kq * 4 + r;
            if (EPI == 0) {
                u16* orow = (u16*)Cout + (size_t)row * N + n0 + wc * 64;
                float v0 = acc[i][0][r] + bs[0], v1 = acc[i][1][r] + bs[1];
                float v2 = acc[i][2][r] + bs[2], v3 = acc[i][3][r] + bs[3];
                *(u32*)(orow + ln * 2)      = pk2(v0, v1);
                *(u32*)(orow + 32 + ln * 2) = pk2(v2, v3);
            } else if (EPI == 1) {
                u16* orow = (u16*)Cout + (size_t)row * N + n0 + wc * 64;
                float v0 = gelu_f(acc[i][0][r] + bs[0]), v1 = gelu_f(acc[i][1][r] + bs[1]);
                float v2 = gelu_f(acc[i][2][r] + bs[2]), v3 = gelu_f(acc[i][3][r] + bs[3]);
                u32x2 pp = { pk2(v0, v1), pk2(v2, v3) };
                *(u32x2*)(orow + ln * 4) = pp;
            } else {   // EPI == 5: final output, write-only scatter
                const int grow = row + rowOff;
                const size_t obase = win_to_img_row(grow) * 512;
                const int cb = n0 + wc * 64;
                u16x4 xv = *(const u16x4*)&X2b[(size_t)grow * 512 + cb + ln * 4];
#pragma unroll
                for (int n = 0; n < 4; ++n)
                    ((float*)Cout)[obase + cb + n * 16 + ln] = bf2f(xv[n]) + acc[i][n][r] + bs[n];
            }
        }
    }
}

// ---------------- proj GEMM + residual + LN2 fused ----------------
// x2 = proj + bias + x  ->  x2b (bf16, WINDOW order, packed p64-permuted)
// LN2(x2)               ->  bufA in-place (bf16, window order, packed permuted)
// XWB=1: residual read from xwb (bf16, window-order, p64 layout — contiguous u16x4)
// XWB=0: residual read from Xres (fp32, image order, scattered)
template <int XWB>
__global__ __launch_bounds__(512) void gemm_pln(
    const u16* __restrict__ A, const u16* __restrict__ W,
    const float* __restrict__ bias, const float* __restrict__ Xres,
    const u16* __restrict__ Xwb,
    const float* __restrict__ g2, const float* __restrict__ b2,
    u16* __restrict__ X2b, u16* Aout)
{
    __shared__ __align__(16) u16 sA[128 * 32];
    __shared__ __align__(16) u16 sB[512 * 32];
    __shared__ float red[128][8];
    const int tid = threadIdx.x;
    const int lane = tid & 63, wv = tid >> 6;
    const int wr = wv >> 2, wc = wv & 3;
    const int ln = lane & 15, kq = lane >> 4;
    const int nwg = gridDim.x;
    const int wgid = (blockIdx.x & 7) * (nwg >> 3) + (blockIdx.x >> 3);
    const int m0 = wgid << 7;

    const int srow = tid >> 2;
    const int scol = ((tid & 3) ^ ((srow >> 1) & 3)) << 3;
    const u16* gA = A + (size_t)(m0 + srow) * 512 + scol;
    const u16* gB = W + (size_t)srow * 512 + scol;

    const int swq = (kq ^ ((ln >> 1) & 3)) << 3;
    const int aoff = (wr * 64 + ln) * 32 + swq;
    const int boff = (wc * 128 + ln) * 32 + swq;

    f32x4 acc[4][8] = {};

    for (int k0 = 0; k0 < 512; k0 += 32) {
        async16(&sA[tid * 8], gA);
        async16(&sB[tid * 8],         gB);
        async16(&sB[4096 + tid * 8],  gB + (size_t)128 * 512);
        async16(&sB[8192 + tid * 8],  gB + (size_t)256 * 512);
        async16(&sB[12288 + tid * 8], gB + (size_t)384 * 512);
        gA += 32; gB += 32;
        __syncthreads();
        bf16x8 af[4], bf[8];
#pragma unroll
        for (int i = 0; i < 4; ++i) af[i] = *(const bf16x8*)&sA[aoff + i * 512];
#pragma unroll
        for (int n = 0; n < 8; ++n) bf[n] = *(const bf16x8*)&sB[boff + n * 512];
        __builtin_amdgcn_s_setprio(1);
#pragma unroll
        for (int i = 0; i < 4; ++i)
#pragma unroll
            for (int n = 0; n < 8; ++n)
                acc[i][n] = __builtin_amdgcn_mfma_f32_16x16x32_bf16(af[i], bf[n], acc[i][n], 0, 0, 0);
        __builtin_amdgcn_s_setprio(0);
        __syncthreads();
    }

    // ---- phase 1: residual, x2b packed store, LN partials (acc := x2) ----
    float bs[8], gg[8], bb[8];
#pragma unroll
    for (int n = 0; n < 8; ++n) {
        int col = wc * 128 + n * 16 + ln;
        bs[n] = bias[col]; gg[n] = g2[col]; bb[n] = b2[col];
    }
#pragma unroll
    for (int i = 0; i < 4; ++i) {
#pragma unroll
        for (int r = 0; r < 4; ++r) {
            const int row = m0 + wr * 64 + i * 16 + kq * 4 + r;
            float o[8], s = 0.f, q = 0.f;
            if (XWB) {
                const u16* xr = Xwb + (size_t)row * 512 + wc * 128 + ln * 4;
                u16x4 xa = *(const u16x4*)xr;
                u16x4 xb = *(const u16x4*)(xr + 64);
#pragma unroll
                for (int n = 0; n < 8; ++n) {
                    float xres = (n < 4) ? bf2f(xa[n]) : bf2f(xb[n - 4]);
                    o[n] = acc[i][n][r] + bs[n] + xres;
                    acc[i][n][r] = o[n];
                    s += o[n]; q += o[n] * o[n];
                }
            } else {
                const size_t ib = win_to_img_row(row) * 512;
#pragma unroll
                for (int n = 0; n < 8; ++n) {
                    const int col = wc * 128 + n * 16 + ln;
                    o[n] = acc[i][n][r] + bs[n] + Xres[ib + col];
                    acc[i][n][r] = o[n];
                    s += o[n]; q += o[n] * o[n];
                }
            }
            u16* xrow = X2b + (size_t)row * 512 + wc * 128 + ln * 4;
            u32x2 p0 = { pk2(o[0], o[1]), pk2(o[2], o[3]) };
            u32x2 p1 = { pk2(o[4], o[5]), pk2(o[6], o[7]) };
            *(u32x2*)xrow        = p0;
            *(u32x2*)(xrow + 64) = p1;
#pragma unroll
            for (int d = 1; d < 16; d <<= 1) { s += __shfl_xor(s, d); q += __shfl_xor(q, d); }
            if (ln == 0) {
                const int lr = wr * 64 + i * 16 + kq * 4 + r;
                red[lr][wc * 2] = s; red[lr][wc * 2 + 1] = q;
            }
        }
    }
    __syncthreads();
    // ---- phase 2: LN2 -> bufA in-place, packed permuted ----
#pragma unroll
    for (int i = 0; i < 4; ++i) {
#pragma unroll
        for (int r = 0; r < 4; ++r) {
            const int lr = wr * 64 + i * 16 + kq * 4 + r;
            const int row = m0 + lr;
            float s = red[lr][0] + red[lr][2] + red[lr][4] + red[lr][6];
            float q = red[lr][1] + red[lr][3] + red[lr][5] + red[lr][7];
            float mean = s * (1.f / 512.f);
            float var  = q * (1.f / 512.f) - mean * mean;
            float rstd = rsqrtf(var + 1e-5f);
            float h[8];
#pragma unroll
            for (int n = 0; n < 8; ++n)
                h[n] = (acc[i][n][r] - mean) * rstd * gg[n] + bb[n];
            u16* arow = Aout + (size_t)row * 512 + wc * 128 + ln * 4;
            u32x2 p0 = { pk2(h[0], h[1]), pk2(h[2], h[3]) };
            u32x2 p1 = { pk2(h[4], h[5]), pk2(h[6], h[7]) };
            *(u32x2*)arow        = p0;
            *(u32x2*)(arow + 64) = p1;
        }
    }
}

// ---------------- MFMA windowed attention ----------------
__global__ __launch_bounds__(256) void attn_kernel(
    const u16* __restrict__ qkv, const float* __restrict__ tbl,
    u16* __restrict__ outp, int wbOff)
{
    __shared__ __align__(16) u16 qb[64][40];
    __shared__ __align__(16) u16 kb[64][40];
    __shared__ __align__(16) u16 vt[32][72];
    __shared__ __align__(16) u16 pb[64][72];

    const int tid = threadIdx.x;
    const int lane = tid & 63, wv = tid >> 6;
    const int wbl = blockIdx.x >> 4, head = blockIdx.x & 15;
    const int wbg = wbl + wbOff;
    const int w = wbg & 63;
    const int cat = (((w >> 3) == 7) ? 2 : 0) + (((w & 7) == 7) ? 1 : 0);
    const size_t base = (size_t)wbl * 49 * 1536 + head * 32;

    const u16x8 zz = {};
    for (int e = tid; e < 75; e += 256) {
        int r = 49 + e / 5, c8 = e % 5;
        *(u16x8*)&kb[r][c8 * 8] = zz;
    }
    for (int e = tid; e < 96; e += 256) {
        int d = e / 3, c8 = e % 3;
        *(u16x8*)&vt[d][48 + c8 * 8] = zz;
    }
    for (int e3 = tid; e3 < 588; e3 += 256) {
        int sel = e3 / 196, e = e3 - sel * 196;
        int r = e >> 2, c8 = e & 3;
        u16x8 v = *(const u16x8*)&qkv[base + (size_t)r * 1536 + sel * 512 + c8 * 8];
        if (sel == 0)      *(u16x8*)&qb[r][c8 * 8] = v;
        else if (sel == 1) *(u16x8*)&kb[r][c8 * 8] = v;
        else {
            // de-permute: slot s = c8*8+j holds original d = (s>>1) + 16*(s&1)
#pragma unroll
            for (int j = 0; j < 8; ++j) vt[c8 * 4 + (j >> 1) + ((j & 1) << 4)][r] = v[j];
        }
    }
    __syncthreads();

    const int ln = lane & 15, kq = lane >> 4;

    bf16x8 a = *(const bf16x8*)&qb[wv * 16 + ln][kq * 8];
    f32x4 acc[4] = {};
#pragma unroll
    for (int j = 0; j < 4; ++j) {
        bf16x8 b = *(const bf16x8*)&kb[j * 16 + ln][kq * 8];
        acc[j] = __builtin_amdgcn_mfma_f32_16x16x32_bf16(a, b, acc[j], 0, 0, 0);
    }

    const float* tb = tbl + (((cat * 16 + head) * 64) + wv * 16 + kq * 4) * 64 + ln;
    const float sc = 0.1767766952966369f;
    float inv[4];
#pragma unroll
    for (int t = 0; t < 4; ++t) {
        float v0 = acc[0][t] * sc + tb[t * 64];
        float v1 = acc[1][t] * sc + tb[t * 64 + 16];
        float v2 = acc[2][t] * sc + tb[t * 64 + 32];
        float v3 = acc[3][t] * sc + tb[t * 64 + 48];
        float m = fmaxf(fmaxf(v0, v1), fmaxf(v2, v3));
#pragma unroll
        for (int d = 1; d < 16; d <<= 1) m = fmaxf(m, __shfl_xor(m, d));
        v0 = __expf(v0 - m); v1 = __expf(v1 - m);
        v2 = __expf(v2 - m); v3 = __expf(v3 - m);
        float s = v0 + v1 + v2 + v3;
#pragma unroll
        for (int d = 1; d < 16; d <<= 1) s += __shfl_xor(s, d);
        inv[t] = 1.f / s;
        const int row = wv * 16 + kq * 4 + t;
        pb[row][ln]      = f2bf(v0);
        pb[row][ln + 16] = f2bf(v1);
        pb[row][ln + 32] = f2bf(v2);
        pb[row][ln + 48] = f2bf(v3);
    }

    f32x4 o[2] = {};
#pragma unroll
    for (int ks = 0; ks < 2; ++ks) {
        bf16x8 pa = *(const bf16x8*)&pb[wv * 16 + ln][ks * 32 + kq * 8];
#pragma unroll
        for (int j2 = 0; j2 < 2; ++j2) {
            bf16x8 vb = *(const bf16x8*)&vt[j2 * 16 + ln][ks * 32 + kq * 8];
            o[j2] = __builtin_amdgcn_mfma_f32_16x16x32_bf16(pa, vb, o[j2], 0, 0, 0);
        }
    }

#pragma unroll
    for (int t = 0; t < 4; ++t) {
        const int r = wv * 16 + kq * 4 + t;
        if (r < 49) {
            const size_t ob = ((size_t)(wbg * 49 + r)) * 512 + head * 32;
#pragma unroll
            for (int j2 = 0; j2 < 2; ++j2)
                outp[ob + j2 * 16 + ln] = f2bf(o[j2][t] * inv[t]);
        }
    }
}

// ---------------- launch ----------------
extern "C" void kernel_launch(void* const* d_in, const int* in_sizes, int n_in,
                              void* d_out, int out_size, void* d_ws, size_t ws_size,
                              hipStream_t stream)
{
    (void)in_sizes; (void)n_in; (void)out_size;
    const float* x     = (const float*)d_in[0];
    const float* n1g   = (const float*)d_in[1];
    const float* n1b   = (const float*)d_in[2];
    const float* qkvw  = (const float*)d_in[3];
    const float* qkvb  = (const float*)d_in[4];
    const float* relb  = (const float*)d_in[5];
    const float* projw = (const float*)d_in[6];
    const float* projb = (const float*)d_in[7];
    const float* n2g   = (const float*)d_in[8];
    const float* n2b   = (const float*)d_in[9];
    const float* fc1w  = (const float*)d_in[10];
    const float* fc1b  = (const float*)d_in[11];
    const float* fc2w  = (const float*)d_in[12];
    const float* fc2b  = (const float*)d_in[13];
    float* out = (float*)d_out;

    char* p = (char*)d_ws;
    u16* wq    = (u16*)p; p += (size_t)786432  * 2;
    u16* wp    = (u16*)p; p += (size_t)262144  * 2;
    u16* w1    = (u16*)p; p += (size_t)1048576 * 2;
    u16* w2    = (u16*)p; p += (size_t)1048576 * 2;
    float* tbl = (float*)p; p += (size_t)262144 * 4;
    u16* bufA  = (u16*)p; p += (size_t)100352 * 512 * 2;   // yw / attn_out / ln2 (in-place)

    const size_t tokB   = (size_t)100352 * 512 * 2;        // 102,760,448
    const size_t usedFx = (size_t)(p - (char*)d_ws);       // weights+tbl+bufA
    // tiers: A = xwb + nch2; B = xwb + nch4; C = no-xwb + nch2; D = no-xwb + nch4
    int nch; bool hasXwb;
    if (ws_size >= usedFx + tokB + (size_t)50176 * 2048 * 2 + tokB)      { hasXwb = true;  nch = 2; }
    else if (ws_size >= usedFx + tokB + (size_t)25088 * 2048 * 2 + tokB) { hasXwb = true;  nch = 4; }
    else if (ws_size >= usedFx + (size_t)50176 * 2048 * 2 + tokB)        { hasXwb = false; nch = 2; }
    else                                                                  { hasXwb = false; nch = 4; }
    u16* xwb = nullptr;
    if (hasXwb) { xwb = (u16*)p; p += tokB; }
    u16* bufB = (u16*)p;                                    // qkv chunk / fc1 chunk
    const int chM = 100352 / nch;
    const int chWB = chM / 49;
    u16* x2b = bufB + (size_t)chM * 2048;                   // past the fc1 chunk

    cvt_kernel<<<3072, 256, 0, stream>>>(qkvw, wq, 786432);
    cvt_kernel<<<1024, 256, 0, stream>>>(projw, wp, 262144);
    cvt_p64k512_kernel<<<4096, 256, 0, stream>>>(fc1w, w1, 1048576);
    cvt_p64_kernel<<<4096, 256, 0, stream>>>(fc2w, w2, 1048576);
    tbl_kernel<<<1024, 256, 0, stream>>>(relb, tbl);

    // LN1 + shift + window partition -> bufA; optionally co-emit xwb (raw x, bf16, p64)
    ln_kernel<<<25088, 256, 0, stream>>>(x, n1g, n1b, bufA, xwb);

    // QKV + attention, chunked
    for (int c = 0; c < nch; ++c) {
        const u16* Ach = bufA + (size_t)c * chM * 512;
        gemm6<0><<<(chM >> 8) * 6, 512, 0, stream>>>(Ach, wq, qkvb, chM, 1536, 512, bufB, 0, nullptr);
        attn_kernel<<<chWB * 16, 256, 0, stream>>>(bufB, tbl, bufA, c * chWB);
    }

    // proj + residual -> x2b (bf16, window order) AND LN2 -> bufA in-place
    if (hasXwb)
        gemm_pln<1><<<784, 512, 0, stream>>>(bufA, wp, projb, x, xwb, n2g, n2b, x2b, bufA);
    else
        gemm_pln<0><<<784, 512, 0, stream>>>(bufA, wp, projb, x, nullptr, n2g, n2b, x2b, bufA);

    // MLP; fc2 writes final out = x2b + mlp, scattered write-only
    for (int c = 0; c < nch; ++c) {
        const u16* Ach = bufA + (size_t)c * chM * 512;
        gemm6<1><<<(chM >> 8) * 8, 512, 0, stream>>>(Ach, w1, fc1b, chM, 2048, 512, bufB, 0, nullptr);
        gemm6<5><<<(chM >> 8) * 2, 512, 0, stream>>>(bufB, w2, fc2b, chM, 512, 2048, out, c * chM, x2b);
    }
}

// Round 15
// 1205.115 us; speedup vs baseline: 1.0471x; 1.0471x over previous
//
#include <hip/hip_runtime.h>

typedef unsigned short u16;
typedef unsigned int u32;
typedef __bf16 bf16x8 __attribute__((ext_vector_type(8)));
typedef __bf16 bf16x2v __attribute__((ext_vector_type(2)));
typedef float f32x4 __attribute__((ext_vector_type(4)));
typedef u16 u16x8 __attribute__((ext_vector_type(8)));
typedef u16 u16x4 __attribute__((ext_vector_type(4)));
typedef u32 u32x2 __attribute__((ext_vector_type(2)));

// ---------------- helpers ----------------
__device__ __forceinline__ u16 f2bf(float f) {
    union { float f; u32 u; } v; v.f = f;
    u32 r = v.u + 0x7fffu + ((v.u >> 16) & 1u);
    return (u16)(r >> 16);
}
__device__ __forceinline__ float bf2f(u16 h) {
    union { u32 u; float f; } v; v.u = ((u32)h) << 16;
    return v.f;
}
__device__ __forceinline__ u32 pk2(float a, float b) {
    bf16x2v t; t[0] = (__bf16)a; t[1] = (__bf16)b;
    union { bf16x2v v; u32 u; } c; c.v = t; return c.u;
}
__device__ __forceinline__ float gelu_f(float x) {
    float x2 = x * x;
    float z = x * fmaf(x2, 0.071354816f, 1.595769122f);
    return x * (1.0f / (1.0f + __expf(-z)));
}
__device__ __forceinline__ void async16(u16* lds, const u16* g) {
    __builtin_amdgcn_global_load_lds(
        (const __attribute__((address_space(1))) void*)g,
        (__attribute__((address_space(3))) void*)lds, 16, 0, 0);
}

// token index (window space) -> source/dest row in (B, 56, 56) raster order
__device__ __forceinline__ size_t win_to_img_row(int td) {
    int wb = td / 49, t = td - wb * 49;
    int bb = wb >> 6, w = wb & 63;
    int wh = w >> 3, ww = w & 7;
    int th = t / 7, tw = t - th * 7;
    int oh = wh * 7 + th + 3; if (oh >= 56) oh -= 56;
    int ow = ww * 7 + tw + 3; if (ow >= 56) ow -= 56;
    return ((size_t)bb * 3136 + oh * 56 + ow);
}

// ---------------- fp32 -> bf16 weight converts ----------------
__global__ void cvt_kernel(const float* __restrict__ s, u16* __restrict__ d, int n) {
    int i = blockIdx.x * 256 + threadIdx.x;
    if (i < n) d[i] = f2bf(s[i]);
}
// within-64 K-column permutation pk(k) = (k&~63) | ((k&15)*4 + ((k>>4)&3))
// fc2 weights, K=2048 (matches fc1's packed EPI1 output layout)
__global__ void cvt_p64_kernel(const float* __restrict__ s, u16* __restrict__ d, int n) {
    int i = blockIdx.x * 256 + threadIdx.x;
    if (i < n) {
        int k = i & 2047, r = i >> 11;
        int pk_ = (k & ~63) | (((k & 15) << 2) | ((k >> 4) & 3));
        d[(r << 11) + pk_] = f2bf(s[i]);
    }
}
// fc1 weights, K=512 (matches gemm_pln's packed LN2 output layout)
__global__ void cvt_p64k512_kernel(const float* __restrict__ s, u16* __restrict__ d, int n) {
    int i = blockIdx.x * 256 + threadIdx.x;
    if (i < n) {
        int k = i & 511, r = i >> 9;
        int pk_ = (k & ~63) | (((k & 15) << 2) | ((k >> 4) & 3));
        d[(r << 9) + pk_] = f2bf(s[i]);
    }
}

// ---------------- bias+mask table: T[cat][head][64][64] fp32 ----------------
__global__ void tbl_kernel(const float* __restrict__ relb, float* __restrict__ T) {
    int i = blockIdx.x * 256 + threadIdx.x;      // 4*16*64*64 = 262144
    int c = i & 63, r = (i >> 6) & 63, head = (i >> 12) & 15, cat = i >> 16;
    float v;
    if (c >= 49 || r >= 49) v = -1e30f;
    else {
        int rh = r / 7, rw = r - rh * 7, ch = c / 7, cw = c - ch * 7;
        v = relb[((rh - ch + 6) * 13 + (rw - cw + 6)) * 16 + head];
        int lr = ((cat & 2) ? (rh < 4 ? 1 : 2) : 0) * 3 + ((cat & 1) ? (rw < 4 ? 1 : 2) : 0);
        int lc = ((cat & 2) ? (ch < 4 ? 1 : 2) : 0) * 3 + ((cat & 1) ? (cw < 4 ? 1 : 2) : 0);
        if (lr != lc) v -= 100.f;
    }
    T[i] = v;
}

// ---------------- LayerNorm (wave per token) + shift+window gather ----------------
__global__ __launch_bounds__(256) void ln_kernel(
    const float* __restrict__ src, const float* __restrict__ g,
    const float* __restrict__ b, u16* __restrict__ dst)
{
    const int lane = threadIdx.x & 63;
    const int td = blockIdx.x * 4 + (threadIdx.x >> 6);
    const size_t so = win_to_img_row(td) * 512;

    const float4* px = (const float4*)(src + so);
    float4 v0 = px[lane * 2], v1 = px[lane * 2 + 1];
    float a[8] = {v0.x, v0.y, v0.z, v0.w, v1.x, v1.y, v1.z, v1.w};
    float s = 0.f, q = 0.f;
#pragma unroll
    for (int e = 0; e < 8; ++e) { s += a[e]; q += a[e] * a[e]; }
#pragma unroll
    for (int m = 32; m; m >>= 1) { s += __shfl_xor(s, m); q += __shfl_xor(q, m); }
    float mean = s * (1.f / 512.f);
    float var  = q * (1.f / 512.f) - mean * mean;
    float rstd = rsqrtf(var + 1e-5f);
    const int c0 = lane * 8;
    u16x8 o;
#pragma unroll
    for (int e = 0; e < 8; ++e)
        o[e] = f2bf((a[e] - mean) * rstd * g[c0 + e] + b[c0 + e]);
    *(u16x8*)(dst + (size_t)td * 512 + c0) = o;
}

// ---------------- 256x256 8-wave 8-phase bf16 GEMM (R9 structure) ----------------
// EPI: 0 = bf16 packed-permuted (qkv), 1 = gelu+bf16 packed-permuted (fc1),
//      5 = final: out[img(row+rowOff)] = bf16(x2b)[row] + acc + bias (nt write-only scatter)
template <int EPI>
__global__ __launch_bounds__(512, 2) void gemm6(
    const u16* __restrict__ A, const u16* __restrict__ W,
    const float* __restrict__ bias, int M, int N, int K,
    void* __restrict__ Cout, int rowOff, const u16* __restrict__ X2b)
{
    __shared__ __align__(16) u16 lds[65536];   // A: [2][256][64] @0, B: [2][256][64] @32768
    const int tid = threadIdx.x;
    const int lane = tid & 63, wv = tid >> 6;
    const int wr = wv >> 2, wc = wv & 3;
    const int ln = lane & 15, kq = lane >> 4;
    const int nbn = N >> 8;
    const int nwg = gridDim.x;
    const int wgid = ((nwg & 7) == 0) ? ((blockIdx.x & 7) * (nwg >> 3) + (blockIdx.x >> 3))
                                      : blockIdx.x;
    const int bm = wgid / nbn, bn = wgid - bm * nbn;
    const int m0 = bm << 8, n0 = bn << 8;

    const int sq = (((tid & 7) ^ ((tid >> 3) & 7)) << 3);
    const u16* gA = A + (size_t)(m0 + (tid >> 3)) * K + sq;
    const u16* gB = W + (size_t)(n0 + (tid >> 3)) * K + sq;

    const int baseA0 = (wr * 128 + ln) * 64 + (((kq) ^ (ln & 7)) << 3);
    const int baseA1 = (wr * 128 + ln) * 64 + (((4 + kq) ^ (ln & 7)) << 3);
    const int baseB0 = 32768 + (wc * 64 + ln) * 64 + (((kq) ^ (ln & 7)) << 3);
    const int baseB1 = 32768 + (wc * 64 + ln) * 64 + (((4 + kq) ^ (ln & 7)) << 3);

#define STA(dd, u, t) async16(lds + (dd) * 16384 + (u) * 4096 + tid * 8, \
                              gA + (size_t)(u) * 64 * K + (size_t)(t) * 64)
#define STB(dd, u, t) async16(lds + 32768 + (dd) * 16384 + (u) * 4096 + tid * 8, \
                              gB + (size_t)(u) * 64 * K + (size_t)(t) * 64)
#define LDA(dd, ms, kh) (*(const bf16x8*)(lds + (dd) * 16384 + ((kh) ? baseA1 : baseA0) + (ms) * 1024))
#define LDB(dd, ns, kh) (*(const bf16x8*)(lds + (dd) * 16384 + ((kh) ? baseB1 : baseB0) + (ns) * 1024))
#define BAR  __builtin_amdgcn_s_barrier()
#define MMQ(mb, nb, BB) do { \
        __builtin_amdgcn_s_setprio(1); \
        _Pragma("unroll") \
        for (int kh = 0; kh < 2; ++kh) \
        _Pragma("unroll") \
        for (int ms = 0; ms < 4; ++ms) \
        _Pragma("unroll") \
        for (int nn = 0; nn < 2; ++nn) \
            acc[(mb) + ms][(nb) + nn] = __builtin_amdgcn_mfma_f32_16x16x32_bf16( \
                af[ms][kh], BB[nn][kh], acc[(mb) + ms][(nb) + nn], 0, 0, 0); \
        __builtin_amdgcn_s_setprio(0); \
    } while (0)

    const int nIter = K >> 7;
    f32x4 acc[8][4] = {};
    bf16x8 af[4][2], b01[2][2], b23[2][2];

    STA(0, 0, 0); STA(0, 2, 0); STA(0, 1, 0); STA(0, 3, 0);
    STB(0, 0, 0); STB(0, 1, 0); STB(0, 2, 0); STB(0, 3, 0);
    STA(1, 0, 1); STA(1, 2, 1); STA(1, 1, 1); STA(1, 3, 1);
    asm volatile("s_waitcnt vmcnt(4)" ::: "memory");
    BAR;

    for (int it = 0; it < nIter; ++it) {
        const int T = 2 * it;
        const bool more = (it + 1 < nIter);
        // ---- P1 ----
#pragma unroll
        for (int ms = 0; ms < 4; ++ms) { af[ms][0] = LDA(0, ms, 0); af[ms][1] = LDA(0, ms, 1); }
#pragma unroll
        for (int nn = 0; nn < 2; ++nn) { b01[nn][0] = LDB(0, nn, 0); b01[nn][1] = LDB(0, nn, 1); }
        STB(1, 0, T + 1); STB(1, 1, T + 1);
        MMQ(0, 0, b01);
        BAR;
        // ---- P2 ----
#pragma unroll
        for (int nn = 0; nn < 2; ++nn) { b23[nn][0] = LDB(0, nn + 2, 0); b23[nn][1] = LDB(0, nn + 2, 1); }
        STB(1, 2, T + 1); STB(1, 3, T + 1);
        MMQ(0, 2, b23);
        BAR;
        // ---- P3 ----
#pragma unroll
        for (int ms = 0; ms < 4; ++ms) { af[ms][0] = LDA(0, ms + 4, 0); af[ms][1] = LDA(0, ms + 4, 1); }
        if (more) { STA(0, 0, T + 2); STA(0, 2, T + 2); }
        MMQ(4, 2, b23);
        BAR;
        // ---- P4 ----
        if (more) { STA(0, 1, T + 2); STA(0, 3, T + 2); }
        MMQ(4, 0, b01);
        if (more) asm volatile("s_waitcnt vmcnt(4)" ::: "memory");
        else      asm volatile("s_waitcnt vmcnt(0)" ::: "memory");
        BAR;
        // ---- P5 ----
#pragma unroll
        for (int ms = 0; ms < 4; ++ms) { af[ms][0] = LDA(1, ms, 0); af[ms][1] = LDA(1, ms, 1); }
#pragma unroll
        for (int nn = 0; nn < 2; ++nn) { b01[nn][0] = LDB(1, nn, 0); b01[nn][1] = LDB(1, nn, 1); }
        if (more) { STB(0, 0, T + 2); STB(0, 1, T + 2); }
        MMQ(0, 0, b01);
        BAR;
        // ---- P6 ----
#pragma unroll
        for (int nn = 0; nn < 2; ++nn) { b23[nn][0] = LDB(1, nn + 2, 0); b23[nn][1] = LDB(1, nn + 2, 1); }
        if (more) { STB(0, 2, T + 2); STB(0, 3, T + 2); }
        MMQ(0, 2, b23);
        BAR;
        // ---- P7 ----
#pragma unroll
        for (int ms = 0; ms < 4; ++ms) { af[ms][0] = LDA(1, ms + 4, 0); af[ms][1] = LDA(1, ms + 4, 1); }
        if (more) { STA(1, 0, T + 3); STA(1, 2, T + 3); }
        MMQ(4, 2, b23);
        BAR;
        // ---- P8 ----
        if (more) { STA(1, 1, T + 3); STA(1, 3, T + 3); }
        MMQ(4, 0, b01);
        if (more) asm volatile("s_waitcnt vmcnt(4)" ::: "memory");
        BAR;
    }
#undef STA
#undef STB
#undef LDA
#undef LDB
#undef BAR
#undef MMQ

    // ---------- epilogue ----------
    float bs[4];
#pragma unroll
    for (int n = 0; n < 4; ++n) bs[n] = bias[n0 + wc * 64 + n * 16 + ln];
#pragma unroll
    for (int i = 0; i < 8; ++i) {
#pragma unroll
        for (int r = 0; r < 4; ++r) {
            const int row = m0 + wr * 128 + i * 16 + kq * 4 + r;
            if (EPI == 0) {
                u16* orow = (u16*)Cout + (size_t)row * N + n0 + wc * 64;
                float v0 = acc[i][0][r] + bs[0], v1 = acc[i][1][r] + bs[1];
                float v2 = acc[i][2][r] + bs[2], v3 = acc[i][3][r] + bs[3];
                *(u32*)(orow + ln * 2)      = pk2(v0, v1);
                *(u32*)(orow + 32 + ln * 2) = pk2(v2, v3);
            } else if (EPI == 1) {
                u16* orow = (u16*)Cout + (size_t)row * N + n0 + wc * 64;
                float v0 = gelu_f(acc[i][0][r] + bs[0]), v1 = gelu_f(acc[i][1][r] + bs[1]);
                float v2 = gelu_f(acc[i][2][r] + bs[2]), v3 = gelu_f(acc[i][3][r] + bs[3]);
                u32x2 pp = { pk2(v0, v1), pk2(v2, v3) };
                *(u32x2*)(orow + ln * 4) = pp;
            } else {   // EPI == 5: final output, non-temporal write-only scatter
                const int grow = row + rowOff;
                const size_t obase = win_to_img_row(grow) * 512;
                const int cb = n0 + wc * 64;
                u16x4 xv = *(const u16x4*)&X2b[(size_t)grow * 512 + cb + ln * 4];
#pragma unroll
                for (int n = 0; n < 4; ++n)
                    __builtin_nontemporal_store(bf2f(xv[n]) + acc[i][n][r] + bs[n],
                                                (float*)Cout + obase + cb + n * 16 + ln);
            }
        }
    }
}

// ---------------- proj GEMM + residual + LN2 fused ----------------
// x2 = proj + bias + x[img]  ->  x2b (bf16, WINDOW order, packed p64-permuted)
// LN2(x2)                    ->  bufA in-place (bf16, window order, packed permuted)
// No fp32 Out write; fc2's EPI5 reconstructs out = x2b + mlp.
__global__ __launch_bounds__(512) void gemm_pln(
    const u16* __restrict__ A, const u16* __restrict__ W,
    const float* __restrict__ bias, const float* __restrict__ Xres,
    const float* __restrict__ g2, const float* __restrict__ b2,
    u16* __restrict__ X2b, u16* Aout)
{
    __shared__ __align__(16) u16 sA[128 * 32];
    __shared__ __align__(16) u16 sB[512 * 32];
    __shared__ float red[128][8];
    const int tid = threadIdx.x;
    const int lane = tid & 63, wv = tid >> 6;
    const int wr = wv >> 2, wc = wv & 3;
    const int ln = lane & 15, kq = lane >> 4;
    const int nwg = gridDim.x;
    const int wgid = (blockIdx.x & 7) * (nwg >> 3) + (blockIdx.x >> 3);
    const int m0 = wgid << 7;

    const int srow = tid >> 2;
    const int scol = ((tid & 3) ^ ((srow >> 1) & 3)) << 3;
    const u16* gA = A + (size_t)(m0 + srow) * 512 + scol;
    const u16* gB = W + (size_t)srow * 512 + scol;

    const int swq = (kq ^ ((ln >> 1) & 3)) << 3;
    const int aoff = (wr * 64 + ln) * 32 + swq;
    const int boff = (wc * 128 + ln) * 32 + swq;

    f32x4 acc[4][8] = {};

    for (int k0 = 0; k0 < 512; k0 += 32) {
        async16(&sA[tid * 8], gA);
        async16(&sB[tid * 8],         gB);
        async16(&sB[4096 + tid * 8],  gB + (size_t)128 * 512);
        async16(&sB[8192 + tid * 8],  gB + (size_t)256 * 512);
        async16(&sB[12288 + tid * 8], gB + (size_t)384 * 512);
        gA += 32; gB += 32;
        __syncthreads();
        bf16x8 af[4], bf[8];
#pragma unroll
        for (int i = 0; i < 4; ++i) af[i] = *(const bf16x8*)&sA[aoff + i * 512];
#pragma unroll
        for (int n = 0; n < 8; ++n) bf[n] = *(const bf16x8*)&sB[boff + n * 512];
        __builtin_amdgcn_s_setprio(1);
#pragma unroll
        for (int i = 0; i < 4; ++i)
#pragma unroll
            for (int n = 0; n < 8; ++n)
                acc[i][n] = __builtin_amdgcn_mfma_f32_16x16x32_bf16(af[i], bf[n], acc[i][n], 0, 0, 0);
        __builtin_amdgcn_s_setprio(0);
        __syncthreads();
    }

    // ---- phase 1: residual, x2b packed store, LN partials (acc := x2) ----
    float bs[8], gg[8], bb[8];
#pragma unroll
    for (int n = 0; n < 8; ++n) {
        int col = wc * 128 + n * 16 + ln;
        bs[n] = bias[col]; gg[n] = g2[col]; bb[n] = b2[col];
    }
#pragma unroll
    for (int i = 0; i < 4; ++i) {
#pragma unroll
        for (int r = 0; r < 4; ++r) {
            const int row = m0 + wr * 64 + i * 16 + kq * 4 + r;
            const size_t ib = win_to_img_row(row) * 512;
            float o[8], s = 0.f, q = 0.f;
#pragma unroll
            for (int n = 0; n < 8; ++n) {
                const int col = wc * 128 + n * 16 + ln;
                o[n] = acc[i][n][r] + bs[n] + Xres[ib + col];
                acc[i][n][r] = o[n];
                s += o[n]; q += o[n] * o[n];
            }
            u16* xrow = X2b + (size_t)row * 512 + wc * 128 + ln * 4;
            u32x2 p0 = { pk2(o[0], o[1]), pk2(o[2], o[3]) };
            u32x2 p1 = { pk2(o[4], o[5]), pk2(o[6], o[7]) };
            *(u32x2*)xrow        = p0;
            *(u32x2*)(xrow + 64) = p1;
#pragma unroll
            for (int d = 1; d < 16; d <<= 1) { s += __shfl_xor(s, d); q += __shfl_xor(q, d); }
            if (ln == 0) {
                const int lr = wr * 64 + i * 16 + kq * 4 + r;
                red[lr][wc * 2] = s; red[lr][wc * 2 + 1] = q;
            }
        }
    }
    __syncthreads();
    // ---- phase 2: LN2 -> bufA in-place, packed permuted ----
#pragma unroll
    for (int i = 0; i < 4; ++i) {
#pragma unroll
        for (int r = 0; r < 4; ++r) {
            const int lr = wr * 64 + i * 16 + kq * 4 + r;
            const int row = m0 + lr;
            float s = red[lr][0] + red[lr][2] + red[lr][4] + red[lr][6];
            float q = red[lr][1] + red[lr][3] + red[lr][5] + red[lr][7];
            float mean = s * (1.f / 512.f);
            float var  = q * (1.f / 512.f) - mean * mean;
            float rstd = rsqrtf(var + 1e-5f);
            float h[8];
#pragma unroll
            for (int n = 0; n < 8; ++n)
                h[n] = (acc[i][n][r] - mean) * rstd * gg[n] + bb[n];
            u16* arow = Aout + (size_t)row * 512 + wc * 128 + ln * 4;
            u32x2 p0 = { pk2(h[0], h[1]), pk2(h[2], h[3]) };
            u32x2 p1 = { pk2(h[4], h[5]), pk2(h[6], h[7]) };
            *(u32x2*)arow        = p0;
            *(u32x2*)(arow + 64) = p1;
        }
    }
}

// ---------------- MFMA windowed attention ----------------
__global__ __launch_bounds__(256) void attn_kernel(
    const u16* __restrict__ qkv, const float* __restrict__ tbl,
    u16* __restrict__ outp, int wbOff)
{
    __shared__ __align__(16) u16 qb[64][40];
    __shared__ __align__(16) u16 kb[64][40];
    __shared__ __align__(16) u16 vt[32][72];
    __shared__ __align__(16) u16 pb[64][72];

    const int tid = threadIdx.x;
    const int lane = tid & 63, wv = tid >> 6;
    const int wbl = blockIdx.x >> 4, head = blockIdx.x & 15;
    const int wbg = wbl + wbOff;
    const int w = wbg & 63;
    const int cat = (((w >> 3) == 7) ? 2 : 0) + (((w & 7) == 7) ? 1 : 0);
    const size_t base = (size_t)wbl * 49 * 1536 + head * 32;

    const u16x8 zz = {};
    for (int e = tid; e < 75; e += 256) {
        int r = 49 + e / 5, c8 = e % 5;
        *(u16x8*)&kb[r][c8 * 8] = zz;
    }
    for (int e = tid; e < 96; e += 256) {
        int d = e / 3, c8 = e % 3;
        *(u16x8*)&vt[d][48 + c8 * 8] = zz;
    }
    for (int e3 = tid; e3 < 588; e3 += 256) {
        int sel = e3 / 196, e = e3 - sel * 196;
        int r = e >> 2, c8 = e & 3;
        u16x8 v = *(const u16x8*)&qkv[base + (size_t)r * 1536 + sel * 512 + c8 * 8];
        if (sel == 0)      *(u16x8*)&qb[r][c8 * 8] = v;
        else if (sel == 1) *(u16x8*)&kb[r][c8 * 8] = v;
        else {
            // de-permute: slot s = c8*8+j holds original d = (s>>1) + 16*(s&1)
#pragma unroll
            for (int j = 0; j < 8; ++j) vt[c8 * 4 + (j >> 1) + ((j & 1) << 4)][r] = v[j];
        }
    }
    __syncthreads();

    const int ln = lane & 15, kq = lane >> 4;

    bf16x8 a = *(const bf16x8*)&qb[wv * 16 + ln][kq * 8];
    f32x4 acc[4] = {};
#pragma unroll
    for (int j = 0; j < 4; ++j) {
        bf16x8 b = *(const bf16x8*)&kb[j * 16 + ln][kq * 8];
        acc[j] = __builtin_amdgcn_mfma_f32_16x16x32_bf16(a, b, acc[j], 0, 0, 0);
    }

    const float* tb = tbl + (((cat * 16 + head) * 64) + wv * 16 + kq * 4) * 64 + ln;
    const float sc = 0.1767766952966369f;
    float inv[4];
#pragma unroll
    for (int t = 0; t < 4; ++t) {
        float v0 = acc[0][t] * sc + tb[t * 64];
        float v1 = acc[1][t] * sc + tb[t * 64 + 16];
        float v2 = acc[2][t] * sc + tb[t * 64 + 32];
        float v3 = acc[3][t] * sc + tb[t * 64 + 48];
        float m = fmaxf(fmaxf(v0, v1), fmaxf(v2, v3));
#pragma unroll
        for (int d = 1; d < 16; d <<= 1) m = fmaxf(m, __shfl_xor(m, d));
        v0 = __expf(v0 - m); v1 = __expf(v1 - m);
        v2 = __expf(v2 - m); v3 = __expf(v3 - m);
        float s = v0 + v1 + v2 + v3;
#pragma unroll
        for (int d = 1; d < 16; d <<= 1) s += __shfl_xor(s, d);
        inv[t] = 1.f / s;
        const int row = wv * 16 + kq * 4 + t;
        pb[row][ln]      = f2bf(v0);
        pb[row][ln + 16] = f2bf(v1);
        pb[row][ln + 32] = f2bf(v2);
        pb[row][ln + 48] = f2bf(v3);
    }

    f32x4 o[2] = {};
#pragma unroll
    for (int ks = 0; ks < 2; ++ks) {
        bf16x8 pa = *(const bf16x8*)&pb[wv * 16 + ln][ks * 32 + kq * 8];
#pragma unroll
        for (int j2 = 0; j2 < 2; ++j2) {
            bf16x8 vb = *(const bf16x8*)&vt[j2 * 16 + ln][ks * 32 + kq * 8];
            o[j2] = __builtin_amdgcn_mfma_f32_16x16x32_bf16(pa, vb, o[j2], 0, 0, 0);
        }
    }

#pragma unroll
    for (int t = 0; t < 4; ++t) {
        const int r = wv * 16 + kq * 4 + t;
        if (r < 49) {
            const size_t ob = ((size_t)(wbg * 49 + r)) * 512 + head * 32;
#pragma unroll
            for (int j2 = 0; j2 < 2; ++j2)
                outp[ob + j2 * 16 + ln] = f2bf(o[j2][t] * inv[t]);
        }
    }
}

// ---------------- launch ----------------
extern "C" void kernel_launch(void* const* d_in, const int* in_sizes, int n_in,
                              void* d_out, int out_size, void* d_ws, size_t ws_size,
                              hipStream_t stream)
{
    (void)in_sizes; (void)n_in; (void)out_size;
    const float* x     = (const float*)d_in[0];
    const float* n1g   = (const float*)d_in[1];
    const float* n1b   = (const float*)d_in[2];
    const float* qkvw  = (const float*)d_in[3];
    const float* qkvb  = (const float*)d_in[4];
    const float* relb  = (const float*)d_in[5];
    const float* projw = (const float*)d_in[6];
    const float* projb = (const float*)d_in[7];
    const float* n2g   = (const float*)d_in[8];
    const float* n2b   = (const float*)d_in[9];
    const float* fc1w  = (const float*)d_in[10];
    const float* fc1b  = (const float*)d_in[11];
    const float* fc2w  = (const float*)d_in[12];
    const float* fc2b  = (const float*)d_in[13];
    float* out = (float*)d_out;

    char* p = (char*)d_ws;
    u16* wq    = (u16*)p; p += (size_t)786432  * 2;
    u16* wp    = (u16*)p; p += (size_t)262144  * 2;
    u16* w1    = (u16*)p; p += (size_t)1048576 * 2;
    u16* w2    = (u16*)p; p += (size_t)1048576 * 2;
    float* tbl = (float*)p; p += (size_t)262144 * 4;
    u16* bufA  = (u16*)p; p += (size_t)100352 * 512 * 2;   // yw / attn_out / ln2 (in-place)
    u16* bufB  = (u16*)p;                                   // qkv chunk / fc1 chunk | x2b

    const size_t fixed = ((size_t)786432 + 262144 + 1048576 + 1048576) * 2
                       + (size_t)262144 * 4 + (size_t)100352 * 512 * 2;
    const size_t x2bBytes = (size_t)100352 * 512 * 2;
    const int nch = (ws_size >= fixed + (size_t)50176 * 2048 * 2 + x2bBytes) ? 2 : 4;
    const int chM = 100352 / nch;          // rows per chunk (multiple of 256 and 49)
    const int chWB = chM / 49;             // window-batches per chunk
    u16* x2b = bufB + (size_t)chM * 2048;  // past the fc1 chunk (qkv chunk is smaller)

    cvt_kernel<<<3072, 256, 0, stream>>>(qkvw, wq, 786432);
    cvt_kernel<<<1024, 256, 0, stream>>>(projw, wp, 262144);
    cvt_p64k512_kernel<<<4096, 256, 0, stream>>>(fc1w, w1, 1048576);
    cvt_p64_kernel<<<4096, 256, 0, stream>>>(fc2w, w2, 1048576);
    tbl_kernel<<<1024, 256, 0, stream>>>(relb, tbl);

    // LN1 + shift + window partition -> bufA (bf16, window layout)
    ln_kernel<<<25088, 256, 0, stream>>>(x, n1g, n1b, bufA);

    // QKV + attention, chunked
    for (int c = 0; c < nch; ++c) {
        const u16* Ach = bufA + (size_t)c * chM * 512;
        gemm6<0><<<(chM >> 8) * 6, 512, 0, stream>>>(Ach, wq, qkvb, chM, 1536, 512, bufB, 0, nullptr);
        attn_kernel<<<chWB * 16, 256, 0, stream>>>(bufB, tbl, bufA, c * chWB);
    }

    // proj + residual -> x2b (bf16, window order) AND LN2 -> bufA in-place
    gemm_pln<<<784, 512, 0, stream>>>(bufA, wp, projb, x, n2g, n2b, x2b, bufA);

    // MLP; fc2 writes final out = x2b + mlp, non-temporal scattered write-only
    for (int c = 0; c < nch; ++c) {
        const u16* Ach = bufA + (size_t)c * chM * 512;
        gemm6<1><<<(chM >> 8) * 8, 512, 0, stream>>>(Ach, w1, fc1b, chM, 2048, 512, bufB, 0, nullptr);
        gemm6<5><<<(chM >> 8) * 2, 512, 0, stream>>>(bufB, w2, fc2b, chM, 512, 2048, out, c * chM, x2b);
    }
}